// Round 12
// baseline (712.758 us; speedup 1.0000x reference)
//
#include <hip/hip_runtime.h>

#define NS 512
#define DF 512
#define NQ 16384

// ws layout (float offsets)
#define WS_MEAN0 0
#define WS_MEAN1 512
#define WS_MEANA 1024
#define WS_CNT   1536
#define WS_V0    2048
#define WS_V1    2560
#define WS_KC    3072
#define WS_M     4096                      // M / P fp32 [2][512][512]
#define WS_PB    (WS_M + 2*DF*DF)          // P bf16 [2][512][512] (ushort), written POST-GJ.
                                           // During GJ its head holds TH[c][2] (T-hat publish).
#define WS_QB    (WS_PB + DF*DF)           // Q bf16 (k_qinit) -- same region as GP
#define WS_GP    WS_QB                     // Gp [8 chunks][2 cls][512][512] f32 (dead after k_asm)
// PM[par][c]: phantom 512x512 pre-state copy matrices, aliasing Gp chunks 6,7
// (dead after k_asm; written by k_pm0/k_fpair strictly after k_asm).
#define WS_TH    WS_PB                     // TH[c][s][4096]

typedef __attribute__((ext_vector_type(8))) short short8;
typedef __attribute__((ext_vector_type(4))) float floatx4;

__device__ __forceinline__ unsigned short f2bf(float f) {
    unsigned u = __float_as_uint(f);
    unsigned r = (u + 0x7fffu + ((u >> 16) & 1u)) >> 16;
    return (unsigned short)r;
}

// readlane for float: raw builtin takes i32 -> bitcast explicitly (R5 bug).
__device__ __forceinline__ float readlane_f(float v, int lane) {
    return __uint_as_float(__builtin_amdgcn_readlane(__float_as_uint(v), lane));
}

__device__ __forceinline__ void load_lds16(const void* g, void* l) {
    __builtin_amdgcn_global_load_lds(
        (const __attribute__((address_space(1))) unsigned int*)g,
        (__attribute__((address_space(3))) unsigned int*)l, 16, 0, 0);
}

__device__ __forceinline__ float* pm_base(float* ws, int par, int c) {
    return ws + WS_GP + (size_t)((6 + par) * 2 + c) * DF * DF;
}

// -------- 64x64 SPD Gauss-Jordan inversion of LDS T (stride 66), 256 thr --------
// Callers MUST __syncthreads() before calling.
__device__ __forceinline__ void gj_invert64(float* T, float (*rbuf)[4][64], int tid) {
    int jl = tid & 63, w = tid >> 6;
    float Tr[16];
#pragma unroll
    for (int m = 0; m < 16; ++m) Tr[m] = T[(w * 16 + m) * 66 + jl];
#pragma unroll
    for (int r = 0; r < 16; ++r) {
        const int q0 = r * 4;
        const int par = r & 1;
        if (w == (q0 >> 4)) {
            const int mb = q0 & 15;
            rbuf[par][0][jl] = Tr[mb + 0];
            rbuf[par][1][jl] = Tr[mb + 1];
            rbuf[par][2][jl] = Tr[mb + 2];
            rbuf[par][3][jl] = Tr[mb + 3];
        }
        __syncthreads();
        float B[4][4];
#pragma unroll
        for (int a = 0; a < 4; ++a)
#pragma unroll
            for (int bb = 0; bb < 4; ++bb) B[a][bb] = rbuf[par][a][q0 + bb];
#pragma unroll
        for (int p = 0; p < 4; ++p) {
            float piv = 1.0f / B[p][p];
#pragma unroll
            for (int j = 0; j < 4; ++j) if (j != p) B[p][j] *= piv;
#pragma unroll
            for (int i = 0; i < 4; ++i) if (i != p) {
                float f = B[i][p];
#pragma unroll
                for (int j = 0; j < 4; ++j) if (j != p) B[i][j] -= f * B[p][j];
                B[i][p] = -f * piv;
            }
            B[p][p] = piv;
        }
        float r0v = rbuf[par][0][jl], r1v = rbuf[par][1][jl];
        float r2v = rbuf[par][2][jl], r3v = rbuf[par][3][jl];
        float nr[4];
#pragma unroll
        for (int a = 0; a < 4; ++a)
            nr[a] = B[a][0] * r0v + B[a][1] * r1v + B[a][2] * r2v + B[a][3] * r3v;
        bool colin = ((jl >> 2) == r);
        int bsel = jl & 3;
        float Bc[4];
#pragma unroll
        for (int a = 0; a < 4; ++a)
            Bc[a] = bsel == 0 ? B[a][0]
                  : (bsel == 1 ? B[a][1] : (bsel == 2 ? B[a][2] : B[a][3]));
#pragma unroll
        for (int m = 0; m < 16; ++m) {
            float cv0 = readlane_f(Tr[m], q0 + 0);
            float cv1 = readlane_f(Tr[m], q0 + 1);
            float cv2 = readlane_f(Tr[m], q0 + 2);
            float cv3 = readlane_f(Tr[m], q0 + 3);
            float g = Tr[m] - (cv0 * nr[0] + cv1 * nr[1] + cv2 * nr[2] + cv3 * nr[3]);
            bool rowin = (((w * 16 + m) >> 2) == r);
            float gcol = -(cv0 * Bc[0] + cv1 * Bc[1] + cv2 * Bc[2] + cv3 * Bc[3]);
            if (rowin) g = nr[m & 3];
            if (colin) g = rowin ? Bc[m & 3] : gcol;
            Tr[m] = g;
        }
    }
#pragma unroll
    for (int m = 0; m < 16; ++m) T[(w * 16 + m) * 66 + jl] = Tr[m];
    __syncthreads();
}

// ---- 64x64 LDS matmul helpers (work matrices stride 68; 68*4B rows keep
// float4 reads 16B-aligned). MODE 0: C=A*B  1: C-=A*B  2: C=-(A*B)  3: C+=A*B
template<int MODE>
__device__ __forceinline__ void mm(float* C, const float* A, int as, const float* B, int tid) {
    __syncthreads();
    int tx = (tid & 15) * 4, ty = (tid >> 4) * 4;
    float acc[4][4];
#pragma unroll
    for (int r = 0; r < 4; ++r)
#pragma unroll
        for (int s = 0; s < 4; ++s)
            acc[r][s] = (MODE == 1 || MODE == 3) ? C[(ty + r) * 68 + tx + s] : 0.f;
#pragma unroll 8
    for (int kk = 0; kk < 64; ++kk) {
        float a[4];
#pragma unroll
        for (int r = 0; r < 4; ++r) a[r] = A[(ty + r) * as + kk];
        float4 bv = *(const float4*)&B[kk * 68 + tx];
#pragma unroll
        for (int r = 0; r < 4; ++r) {
            if (MODE == 1) {
                acc[r][0] -= a[r] * bv.x; acc[r][1] -= a[r] * bv.y;
                acc[r][2] -= a[r] * bv.z; acc[r][3] -= a[r] * bv.w;
            } else {
                acc[r][0] += a[r] * bv.x; acc[r][1] += a[r] * bv.y;
                acc[r][2] += a[r] * bv.z; acc[r][3] += a[r] * bv.w;
            }
        }
    }
#pragma unroll
    for (int r = 0; r < 4; ++r)
#pragma unroll
        for (int s = 0; s < 4; ++s)
            C[(ty + r) * 68 + tx + s] = (MODE == 2) ? -acc[r][s] : acc[r][s];
}

// load 64x64 tile global(stride 512) -> LDS(stride 68)
__device__ __forceinline__ void ld_tile(float* d, const float* s, int tid) {
    __syncthreads();
    int tx = (tid & 15) * 4, ty = tid >> 4;
#pragma unroll
    for (int m = 0; m < 4; ++m) {
        int row = ty + m * 16;
        *(float4*)&d[row * 68 + tx] = *(const float4*)&s[(size_t)row * 512 + tx];
    }
}
// load global tile -> LDS stride 66
__device__ __forceinline__ void ld66(float* T, const float* s, int tid) {
    __syncthreads();
#pragma unroll
    for (int m = 0; m < 16; ++m) {
        int idx = tid + 256 * m;
        int i = idx >> 6, j = idx & 63;
        T[i * 66 + j] = s[(size_t)i * 512 + j];
    }
}
__device__ __forceinline__ void cp68to66(float* T, const float* s, int tid) {
    __syncthreads();
#pragma unroll
    for (int m = 0; m < 16; ++m) {
        int idx = tid + 256 * m;
        int i = idx >> 6, j = idx & 63;
        T[i * 66 + j] = s[i * 68 + j];
    }
}
__device__ __forceinline__ void cp68(float* d, const float* s, int tid) {
    __syncthreads();
#pragma unroll
    for (int m = 0; m < 16; ++m) {
        int idx = tid + 256 * m;
        int i = idx >> 6, j = idx & 63;
        d[i * 68 + j] = s[i * 68 + j];
    }
}
// T-hat publish: LDS(66) -> global flat 64x64
__device__ __forceinline__ void st_th(float* th, const float* T, int tid) {
    __syncthreads();
#pragma unroll
    for (int m = 0; m < 16; ++m) {
        int idx = tid + 256 * m;
        int i = idx >> 6, j = idx & 63;
        th[i * 64 + j] = T[i * 66 + j];
    }
}
// T-hat load: global flat -> LDS(68)
__device__ __forceinline__ void ld_th(float* d, const float* th, int tid) {
    __syncthreads();
#pragma unroll
    for (int m = 0; m < 16; ++m) {
        int idx = tid + 256 * m;
        int i = idx >> 6, j = idx & 63;
        d[i * 68 + j] = th[i * 64 + j];
    }
}
// store LDS(68) -> M tile (+ optional PM copy)
__device__ __forceinline__ void st_out(float* mdst, float* pmdst, int emit,
                                       const float* s, int tid) {
    __syncthreads();
    int tx = (tid & 15) * 4, ty = tid >> 4;
#pragma unroll
    for (int m = 0; m < 4; ++m) {
        int row = ty + m * 16;
        float4 v = *(const float4*)&s[row * 68 + tx];
        *(float4*)&mdst[(size_t)row * 512 + tx] = v;
        if (emit) *(float4*)&pmdst[(size_t)row * 512 + tx] = v;
    }
}

// assemble class-c tile (a,bb) of M from Gram partials -> LDS W (stride st)
// (identical expression order to k_asm's tile blocks -> bit-identical values)
__device__ __forceinline__ void asm_tileW(float* W, int st, int a, int bb, int c,
                                          const float* ws, int tid) {
    __syncthreads();
    const float* Gp = ws + WS_GP;
    float n0 = ws[WS_CNT], n1 = ws[WS_CNT + 1];
    float lam0 = fminf(n0 / (n0 + 1.f), 0.1f);
    float lam1 = fminf(n1 / (n1 + 1.f), 0.1f);
    int tx = tid & 15, ty = tid >> 4;
    int jb = bb * 64 + tx * 4;
    float4 m0j = *(const float4*)&ws[WS_MEAN0 + jb];
    float4 m1j = *(const float4*)&ws[WS_MEAN1 + jb];
    float4 maj = *(const float4*)&ws[WS_MEANA + jb];
#pragma unroll
    for (int r = 0; r < 4; ++r) {
        int i = a * 64 + ty * 4 + r;
        float m0i = ws[WS_MEAN0 + i], m1i = ws[WS_MEAN1 + i], mai = ws[WS_MEANA + i];
        float4 g0 = make_float4(0.f, 0.f, 0.f, 0.f);
        float4 g1 = make_float4(0.f, 0.f, 0.f, 0.f);
#pragma unroll
        for (int ch = 0; ch < 8; ++ch) {
            float4 aa = *(const float4*)&Gp[((size_t)(ch * 2 + 0) * DF + i) * DF + jb];
            float4 bb2 = *(const float4*)&Gp[((size_t)(ch * 2 + 1) * DF + i) * DF + jb];
            g0.x += aa.x; g0.y += aa.y; g0.z += aa.z; g0.w += aa.w;
            g1.x += bb2.x; g1.y += bb2.y; g1.z += bb2.z; g1.w += bb2.w;
        }
        float g0a[4] = {g0.x, g0.y, g0.z, g0.w};
        float g1a[4] = {g1.x, g1.y, g1.z, g1.w};
        float m0ja[4] = {m0j.x, m0j.y, m0j.z, m0j.w};
        float m1ja[4] = {m1j.x, m1j.y, m1j.z, m1j.w};
        float maja[4] = {maj.x, maj.y, maj.z, maj.w};
#pragma unroll
        for (int s = 0; s < 4; ++s) {
            int j = jb + s;
            float task = (g0a[s] + g1a[s] - (float)NS * mai * maja[s]) / (float)(NS - 1);
            float cov0 = (g0a[s] - n0 * m0i * m0ja[s]) / (n0 - 1.f);
            float cov1 = (g1a[s] - n1 * m1i * m1ja[s]) / (n1 - 1.f);
            float dg = (i == j) ? 0.1f : 0.f;
            float o0 = lam0 * cov0 + (1.f - lam0) * task + dg;
            float o1 = lam1 * cov1 + (1.f - lam1) * task + dg;
            W[(ty * 4 + r) * st + tx * 4 + s] = c ? o1 : o0;
        }
    }
}

// ---------------- K1: fused stats (blocks 512..519) + masked Grams (0..511) ----------------
__global__ __launch_bounds__(256) void k_front(const float* __restrict__ S,
                                               const int* __restrict__ lab,
                                               float* __restrict__ ws) {
    int b = blockIdx.x, tid = threadIdx.x;
    if (b >= 512) {
        __shared__ int slb[NS];
        __shared__ float r0[4][64], r1[4][64];
        __shared__ int rc[4];
        int bs = b - 512;
        for (int l = tid; l < NS; l += 256) slb[l] = lab[l];
        __syncthreads();
        int dl = tid & 63, ch = tid >> 6;
        int dd = bs * 64 + dl;
        float s0 = 0.f, s1 = 0.f;
        int n1 = 0;
        for (int n = ch * 128; n < ch * 128 + 128; ++n) {
            float v = S[n * DF + dd];
            if (slb[n]) { s1 += v; n1++; } else { s0 += v; }
        }
        r0[ch][dl] = s0; r1[ch][dl] = s1;
        if (dl == 0) rc[ch] = n1;
        __syncthreads();
        if (ch == 0) {
            float t0 = 0.f, t1 = 0.f; int n1t = 0;
#pragma unroll
            for (int x = 0; x < 4; ++x) { t0 += r0[x][dl]; t1 += r1[x][dl]; n1t += rc[x]; }
            float fn1 = (float)n1t, fn0 = (float)(NS - n1t);
            ws[WS_MEAN0 + dd] = t0 / fn0;
            ws[WS_MEAN1 + dd] = t1 / fn1;
            ws[WS_MEANA + dd] = (t0 + t1) / (float)NS;
            if (bs == 0 && dl == 0) {
                ws[WS_CNT] = fn0; ws[WS_CNT + 1] = fn1;
                ws[WS_KC] = 0.f; ws[WS_KC + 1] = 0.f;
            }
        }
        return;
    }
    __shared__ float SA[16 * 65];
    __shared__ float SB[16 * 65];
    __shared__ int lb[16];
    int tx = tid & 15, ty = tid >> 4;
    int i0 = (b & 7) * 64, j0 = ((b >> 3) & 7) * 64;
    int z = b >> 6;
    float a0[4][4] = {{0.f}}, a1[4][4] = {{0.f}};
    for (int nc = z * 64; nc < z * 64 + 64; nc += 16) {
#pragma unroll
        for (int l = 0; l < 4; ++l) {
            int idx = tid + 256 * l;
            int nn = idx >> 6, col = idx & 63;
            SA[nn * 65 + col] = S[(nc + nn) * DF + i0 + col];
            SB[nn * 65 + col] = S[(nc + nn) * DF + j0 + col];
        }
        if (tid < 16) lb[tid] = lab[nc + tid];
        __syncthreads();
#pragma unroll
        for (int kk = 0; kk < 16; ++kk) {
            float av[4], bv[4];
#pragma unroll
            for (int r = 0; r < 4; ++r) av[r] = SA[kk * 65 + ty * 4 + r];
#pragma unroll
            for (int s = 0; s < 4; ++s) bv[s] = SB[kk * 65 + tx * 4 + s];
            if (lb[kk]) {
#pragma unroll
                for (int r = 0; r < 4; ++r)
#pragma unroll
                    for (int s = 0; s < 4; ++s) a1[r][s] += av[r] * bv[s];
            } else {
#pragma unroll
                for (int r = 0; r < 4; ++r)
#pragma unroll
                    for (int s = 0; s < 4; ++s) a0[r][s] += av[r] * bv[s];
            }
        }
        __syncthreads();
    }
    float* Gp = ws + WS_GP;
#pragma unroll
    for (int r = 0; r < 4; ++r) {
        int i = i0 + ty * 4 + r;
#pragma unroll
        for (int s = 0; s < 4; ++s) {
            int j = j0 + tx * 4 + s;
            Gp[((z * 2 + 0) * DF + i) * DF + j] = a0[r][s];
            Gp[((z * 2 + 1) * DF + i) * DF + j] = a1[r][s];
        }
    }
}

// ---------------- K2: assemble M_c (64 tile blocks) + T-hat_0/T-hat_1 chains ----------------
// b<64: full tile both classes -> M. b=64/65: class (b-64) pivot chain:
// T0 = inv(M(0,0)); A = M(1,1) - M(1,0)*T0*M(0,1); T1 = inv(A) -> TH.
// Pivot blocks only READ Gp (assembling their own tiles redundantly,
// bit-identical) -> no race with tile blocks' M writes.
__global__ __launch_bounds__(256) void k_asm(float* __restrict__ ws) {
    int b = blockIdx.x, tid = threadIdx.x;
    __shared__ float T[64 * 66];
    __shared__ float rbuf[2][4][64];
    __shared__ float A1[64 * 68];
    __shared__ float A2[64 * 68];
    __shared__ float A3[64 * 68];
    if (b < 64) {
        const float* Gp = ws + WS_GP;
        float n0 = ws[WS_CNT], n1 = ws[WS_CNT + 1];
        float lam0 = fminf(n0 / (n0 + 1.f), 0.1f);
        float lam1 = fminf(n1 / (n1 + 1.f), 0.1f);
        int ti = b >> 3, tj = b & 7;
        int tx = tid & 15, ty = tid >> 4;
        int jb = tj * 64 + tx * 4;
        float4 m0j = *(const float4*)&ws[WS_MEAN0 + jb];
        float4 m1j = *(const float4*)&ws[WS_MEAN1 + jb];
        float4 maj = *(const float4*)&ws[WS_MEANA + jb];
#pragma unroll
        for (int r = 0; r < 4; ++r) {
            int i = ti * 64 + ty * 4 + r;
            float m0i = ws[WS_MEAN0 + i], m1i = ws[WS_MEAN1 + i], mai = ws[WS_MEANA + i];
            float4 g0 = make_float4(0.f, 0.f, 0.f, 0.f);
            float4 g1 = make_float4(0.f, 0.f, 0.f, 0.f);
#pragma unroll
            for (int ch = 0; ch < 8; ++ch) {
                float4 a = *(const float4*)&Gp[((size_t)(ch * 2 + 0) * DF + i) * DF + jb];
                float4 bb = *(const float4*)&Gp[((size_t)(ch * 2 + 1) * DF + i) * DF + jb];
                g0.x += a.x; g0.y += a.y; g0.z += a.z; g0.w += a.w;
                g1.x += bb.x; g1.y += bb.y; g1.z += bb.z; g1.w += bb.w;
            }
            float g0a[4] = {g0.x, g0.y, g0.z, g0.w};
            float g1a[4] = {g1.x, g1.y, g1.z, g1.w};
            float m0ja[4] = {m0j.x, m0j.y, m0j.z, m0j.w};
            float m1ja[4] = {m1j.x, m1j.y, m1j.z, m1j.w};
            float maja[4] = {maj.x, maj.y, maj.z, maj.w};
            float o0[4], o1[4];
#pragma unroll
            for (int s = 0; s < 4; ++s) {
                int j = jb + s;
                float task = (g0a[s] + g1a[s] - (float)NS * mai * maja[s]) / (float)(NS - 1);
                float cov0 = (g0a[s] - n0 * m0i * m0ja[s]) / (n0 - 1.f);
                float cov1 = (g1a[s] - n1 * m1i * m1ja[s]) / (n1 - 1.f);
                float dg = (i == j) ? 0.1f : 0.f;
                o0[s] = lam0 * cov0 + (1.f - lam0) * task + dg;
                o1[s] = lam1 * cov1 + (1.f - lam1) * task + dg;
            }
            *(float4*)&ws[WS_M + (size_t)i * DF + jb] = make_float4(o0[0], o0[1], o0[2], o0[3]);
            *(float4*)&ws[WS_M + DF * DF + (size_t)i * DF + jb] = make_float4(o1[0], o1[1], o1[2], o1[3]);
        }
        return;
    }
    // pivot chain for class c
    int c = b - 64;
    asm_tileW(T, 66, 0, 0, c, ws, tid);
    __syncthreads();
    gj_invert64(T, rbuf, tid);
    st_th(ws + WS_TH + (c * 2 + 0) * 4096, T, tid);
    asm_tileW(A1, 68, 0, 1, c, ws, tid);
    mm<0>(A2, T, 66, A1, tid);                 // D1 = T0 * M(0,1)
    asm_tileW(A1, 68, 1, 0, c, ws, tid);
    asm_tileW(A3, 68, 1, 1, c, ws, tid);
    mm<1>(A3, A1, 68, A2, tid);                // A = M(1,1) - M(1,0)*D1
    cp68to66(T, A3, tid);
    __syncthreads();
    gj_invert64(T, rbuf, tid);
    st_th(ws + WS_TH + (c * 2 + 1) * 4096, T, tid);
}

// ---------------- K2b: seed PM[0] with pre-state rows/cols 0,1 (copies of M) ----------------
__global__ __launch_bounds__(256) void k_pm0(float* __restrict__ ws) {
    int idx = blockIdx.x, c = blockIdx.y, tid = threadIdx.x;
    int ti, tj;
    if (idx < 16) { ti = idx >> 3; tj = idx & 7; }           // rows 0,1 (all tj)
    else { int rem = idx - 16; ti = 2 + (rem >> 1); tj = rem & 1; }  // cols 0,1, ti>=2
    const float* src = ws + WS_M + (size_t)c * DF * DF + (size_t)(ti * 64) * 512 + tj * 64;
    float* dst = pm_base(ws, 0, c) + (size_t)(ti * 64) * 512 + tj * 64;
    int tx = (tid & 15) * 4, ty = tid >> 4;
#pragma unroll
    for (int m = 0; m < 4; ++m) {
        int row = ty + m * 16;
        *(float4*)&dst[(size_t)row * 512 + tx] = *(const float4*)&src[(size_t)row * 512 + tx];
    }
}

// ---------------- K3a: pair prep (L>=1): T-hat_k, T-hat_{k+1} from PM[par] ----------------
__global__ __launch_bounds__(256) void k_prep(float* __restrict__ ws, int L) {
    int c = blockIdx.x, tid = threadIdx.x;
    int k = 2 * L, k2 = k + 1, par = L & 1;
    __shared__ float T[64 * 66];
    __shared__ float rbuf[2][4][64];
    __shared__ float A1[64 * 68];
    __shared__ float A2[64 * 68];
    __shared__ float A3[64 * 68];
    float* PM = pm_base(ws, par, c);
    ld66(T, PM + (size_t)(k * 64) * 512 + k * 64, tid);
    __syncthreads();
    gj_invert64(T, rbuf, tid);
    st_th(ws + WS_TH + (c * 2 + 0) * 4096, T, tid);
    ld_tile(A1, PM + (size_t)(k * 64) * 512 + k2 * 64, tid);
    mm<0>(A2, T, 66, A1, tid);                 // D1 = Tk * PM(k,k2)
    ld_tile(A1, PM + (size_t)(k2 * 64) * 512 + k * 64, tid);
    ld_tile(A3, PM + (size_t)(k2 * 64) * 512 + k2 * 64, tid);
    mm<1>(A3, A1, 68, A2, tid);                // A = PM(k2,k2) - PM(k2,k)*D1
    cp68to66(T, A3, tid);
    __syncthreads();
    gj_invert64(T, rbuf, tid);
    st_th(ws + WS_TH + (c * 2 + 1) * 4096, T, tid);
}

// ---------------- K3b: fused two-step GJ pair update ----------------
// Every block computes its tile's value after steps k=2L and k+1, purely from
// pre-pair state (PM[par] copies + published T-hats) + its own M tile.
// Writes: own M tile (+ PM[npar] copy if tile in rows/cols k+2,k+3). No
// intra-launch read-write overlap.
__global__ __launch_bounds__(256) void k_fpair(float* __restrict__ ws, int L) {
    int x = blockIdx.x, c = blockIdx.y, tid = threadIdx.x;
    int ti = x >> 3, tj = x & 7;
    int k = 2 * L, k2 = k + 1, par = L & 1, npar = par ^ 1;
    __shared__ float BT[64 * 68];   // T-hat_k
    __shared__ float BS[64 * 68];   // T-hat_{k+1}
    __shared__ float A1[64 * 68];
    __shared__ float A2[64 * 68];
    __shared__ float A3[64 * 68];
    __shared__ float A4[64 * 68];
    __shared__ float A5[64 * 68];
    float* PM = pm_base(ws, par, c);
    float* PMo = pm_base(ws, npar, c);
    float* Mb = ws + WS_M + (size_t)c * DF * DF;
    float* mdst = Mb + (size_t)(ti * 64) * 512 + tj * 64;
    int p0 = k + 2, p1 = k + 3;
    int emit = (L < 3) && (ti == p0 || ti == p1 || tj == p0 || tj == p1);
    float* pmdst = PMo + (size_t)(ti * 64) * 512 + tj * 64;
    const float* th0 = ws + WS_TH + (c * 2 + 0) * 4096;
    const float* th1 = ws + WS_TH + (c * 2 + 1) * 4096;
#define PMT(a, b) (PM + (size_t)((a) * 64) * 512 + (b) * 64)

    ld_th(BT, th0, tid);
    ld_th(BS, th1, tid);

    if (ti == k && tj == k) {
        // out = Tk - Rk2 * Tk2 * Ck2
        ld_tile(A1, PMT(k, k2), tid);
        mm<0>(A2, BT, 68, A1, tid);            // Rk2
        ld_tile(A4, PMT(k2, k), tid);
        mm<0>(A3, A4, 68, BT, tid);            // -Ck2
        mm<0>(A1, BS, 68, A3, tid);            // -Tk2*Ck2
        cp68(A5, BT, tid);
        mm<3>(A5, A2, 68, A1, tid);            // Tk + Rk2*(Tk2*Ck2-neg) = out
        st_out(mdst, pmdst, emit, A5, tid);
        return;
    }
    if (ti == k && tj == k2) {
        // out = -Rk2 * Tk2
        ld_tile(A1, PMT(k, k2), tid);
        mm<0>(A2, BT, 68, A1, tid);            // Rk2
        mm<2>(A3, A2, 68, BS, tid);
        st_out(mdst, pmdst, emit, A3, tid);
        return;
    }
    if (ti == k2 && tj == k) {
        // out = Tk2 * Ck2 = -Tk2 * (PM(k2,k)*Tk)
        ld_tile(A4, PMT(k2, k), tid);
        mm<0>(A3, A4, 68, BT, tid);            // -Ck2
        mm<2>(A2, BS, 68, A3, tid);
        st_out(mdst, pmdst, emit, A2, tid);
        return;
    }
    if (ti == k2 && tj == k2) {
        st_out(mdst, pmdst, emit, BS, tid);    // out = Tk2
        return;
    }
    if (ti == k) {
        // out = Rtj - Rk2 * (Tk2 * Y1(k2,tj))
        ld_tile(A1, PMT(k, tj), tid);
        mm<0>(A2, BT, 68, A1, tid);            // Rtj
        ld_tile(A1, PMT(k2, k), tid);
        ld_tile(A3, PMT(k2, tj), tid);
        mm<1>(A3, A1, 68, A2, tid);            // Y1(k2,tj)
        mm<0>(A4, BS, 68, A3, tid);            // D
        ld_tile(A1, PMT(k, k2), tid);
        mm<0>(A3, BT, 68, A1, tid);            // Rk2
        mm<1>(A2, A3, 68, A4, tid);            // out
        st_out(mdst, pmdst, emit, A2, tid);
        return;
    }
    if (ti == k2) {
        // out = Tk2 * Y1(k2,tj)
        ld_tile(A1, PMT(k, tj), tid);
        mm<0>(A2, BT, 68, A1, tid);            // Rtj
        ld_tile(A1, PMT(k2, k), tid);
        ld_tile(A3, PMT(k2, tj), tid);
        mm<1>(A3, A1, 68, A2, tid);            // Y1(k2,tj)
        mm<0>(A2, BS, 68, A3, tid);
        st_out(mdst, pmdst, emit, A2, tid);
        return;
    }
    if (tj == k) {
        // out = Cti - Y1(ti,k2) * (Tk2 * Ck2)  [= Cti + Y1*(Tk2*(-Ck2))]
        ld_tile(A4, PMT(ti, k), tid);
        mm<2>(A2, A4, 68, BT, tid);            // Cti
        ld_tile(A1, PMT(k, k2), tid);
        mm<0>(A3, BT, 68, A1, tid);            // Rk2
        ld_tile(A1, PMT(ti, k2), tid);
        mm<1>(A1, A4, 68, A3, tid);            // Y1(ti,k2)
        ld_tile(A4, PMT(k2, k), tid);
        mm<0>(A3, A4, 68, BT, tid);            // -Ck2
        mm<0>(A4, BS, 68, A3, tid);            // -D
        mm<3>(A2, A1, 68, A4, tid);            // Cti + Y1*(-D*-1)... = Cti - Y1*D
        st_out(mdst, pmdst, emit, A2, tid);
        return;
    }
    if (tj == k2) {
        // out = -Y1(ti,k2) * Tk2
        ld_tile(A4, PMT(ti, k), tid);
        ld_tile(A1, PMT(k, k2), tid);
        mm<0>(A3, BT, 68, A1, tid);            // Rk2
        ld_tile(A1, PMT(ti, k2), tid);
        mm<1>(A1, A4, 68, A3, tid);            // Y1(ti,k2)
        mm<2>(A2, A1, 68, BS, tid);
        st_out(mdst, pmdst, emit, A2, tid);
        return;
    }
    // trailing: out = Y1own - Y1(ti,k2) * (Tk2 * Y1(k2,tj))
    ld_tile(A1, PMT(k, tj), tid);
    mm<0>(A2, BT, 68, A1, tid);                // Rtj
    ld_tile(A1, PMT(k2, k), tid);
    ld_tile(A3, PMT(k2, tj), tid);
    mm<1>(A3, A1, 68, A2, tid);                // Y1(k2,tj)
    ld_tile(A4, PMT(ti, k), tid);
    ld_tile(A5, mdst, tid);
    mm<1>(A5, A4, 68, A2, tid);                // Y1own
    ld_tile(A1, PMT(k, k2), tid);
    mm<0>(A2, BT, 68, A1, tid);                // Rk2
    ld_tile(A1, PMT(ti, k2), tid);
    mm<1>(A1, A4, 68, A2, tid);                // Y1(ti,k2)
    mm<0>(A2, BS, 68, A3, tid);                // D
    mm<1>(A5, A1, 68, A2, tid);                // out
    st_out(mdst, pmdst, emit, A5, tid);
#undef PMT
}

// ---------------- K4: v_c/k_c (blocks 0..15) + P fp32 -> bf16 (blocks 16..271) ----------------
__global__ __launch_bounds__(256) void k_vkbf(float* __restrict__ ws) {
    int b = blockIdx.x;
    int tid = threadIdx.x;
    if (b >= 16) {
        int e = (b - 16) * 2048 + tid * 8;
        const float* M = ws + WS_M;
        unsigned short* pbw = (unsigned short*)(ws + WS_PB);
        float4 x0 = *(const float4*)&M[e];
        float4 x1 = *(const float4*)&M[e + 4];
        short8 r;
        r[0] = (short)f2bf(x0.x); r[1] = (short)f2bf(x0.y);
        r[2] = (short)f2bf(x0.z); r[3] = (short)f2bf(x0.w);
        r[4] = (short)f2bf(x1.x); r[5] = (short)f2bf(x1.y);
        r[6] = (short)f2bf(x1.z); r[7] = (short)f2bf(x1.w);
        *(short8*)(pbw + e) = r;
        return;
    }
    int c = b >> 3, rb = b & 7;
    const float* P = ws + WS_M + (size_t)c * DF * DF;
    const float* mc = ws + (c ? WS_MEAN1 : WS_MEAN0);
    float* v = ws + (c ? WS_V1 : WS_V0);
    __shared__ float ml[DF];
    __shared__ float red[4][64];
    for (int l = tid; l < DF; l += 256) ml[l] = mc[l];
    __syncthreads();
    int rl = tid & 63, ch = tid >> 6;
    int row = rb * 64 + rl;
    float dot = 0.f;
    const float* pr = P + (size_t)row * DF + ch * 128;
    for (int t = 0; t < 32; ++t) {
        float4 pv = *(const float4*)(pr + t * 4);
        const float* mm2 = ml + ch * 128 + t * 4;
        dot += pv.x * mm2[0] + pv.y * mm2[1] + pv.z * mm2[2] + pv.w * mm2[3];
    }
    red[ch][rl] = dot;
    __syncthreads();
    if (ch == 0) {
        float d = red[0][rl] + red[1][rl] + red[2][rl] + red[3][rl];
        v[row] = d;
        float kp = d * ml[row];
#pragma unroll
        for (int off = 32; off > 0; off >>= 1) kp += __shfl_down(kp, off);
        if (rl == 0) atomicAdd(&ws[WS_KC + c], kp);
    }
}

// ---------------- K5: fused Q->bf16 + logits init ----------------
__global__ __launch_bounds__(256) void k_qinit(const float* __restrict__ Q,
                                               float* __restrict__ ws,
                                               float* __restrict__ out) {
    unsigned short* qbw = (unsigned short*)(ws + WS_QB);
    const float* v0 = ws + WS_V0;
    const float* v1 = ws + WS_V1;
    int lane = threadIdx.x & 63;
    int q = blockIdx.x * 4 + (threadIdx.x >> 6);
    const float* qrow = Q + (size_t)q * DF + lane * 8;
    float4 x0 = *(const float4*)(qrow);
    float4 x1 = *(const float4*)(qrow + 4);
    const float* v0p = v0 + lane * 8;
    const float* v1p = v1 + lane * 8;
    float4 w00 = *(const float4*)(v0p), w01 = *(const float4*)(v0p + 4);
    float4 w10 = *(const float4*)(v1p), w11 = *(const float4*)(v1p + 4);
    float a0 = x0.x * w00.x + x0.y * w00.y + x0.z * w00.z + x0.w * w00.w
             + x1.x * w01.x + x1.y * w01.y + x1.z * w01.z + x1.w * w01.w;
    float a1 = x0.x * w10.x + x0.y * w10.y + x0.z * w10.z + x0.w * w10.w
             + x1.x * w11.x + x1.y * w11.y + x1.z * w11.z + x1.w * w11.w;
    short8 r;
    r[0] = (short)f2bf(x0.x); r[1] = (short)f2bf(x0.y);
    r[2] = (short)f2bf(x0.z); r[3] = (short)f2bf(x0.w);
    r[4] = (short)f2bf(x1.x); r[5] = (short)f2bf(x1.y);
    r[6] = (short)f2bf(x1.z); r[7] = (short)f2bf(x1.w);
    *(short8*)(qbw + (size_t)q * DF + lane * 8) = r;
#pragma unroll
    for (int off = 32; off > 0; off >>= 1) {
        a0 += __shfl_down(a0, off);
        a1 += __shfl_down(a1, off);
    }
    if (lane == 0) {
        out[q * 2 + 0] = 2.f * a0 - ws[WS_KC + 0];
        out[q * 2 + 1] = 2.f * a1 - ws[WS_KC + 1];
    }
}

// ---------------- K6: MFMA GEMM, 128x128 tile, LDS staging + swizzle ----------------
__global__ __launch_bounds__(256, 3) void k_gemm(const float* __restrict__ ws,
                                                 float* __restrict__ out) {
    const unsigned short* qb = (const unsigned short*)(ws + WS_QB);
    int c = blockIdx.y >> 2;
    int n0 = (blockIdx.y & 3) * 128;
    const unsigned short* pbc = (const unsigned short*)(ws + WS_PB) + (size_t)c * DF * DF;
    int q0 = blockIdx.x * 128;
    __shared__ __align__(16) unsigned short Abuf[128 * 64];
    __shared__ __align__(16) unsigned short Bbuf[128 * 64];
    int tid = threadIdx.x;
    int w = tid >> 6, lane = tid & 63;
    int quad = lane >> 4, l15 = lane & 15;
    floatx4 acc[2][8];
#pragma unroll
    for (int mt = 0; mt < 2; ++mt)
#pragma unroll
        for (int nt = 0; nt < 8; ++nt) acc[mt][nt] = (floatx4)(0.f);

    for (int kt = 0; kt < 8; ++kt) {
        int kc2 = kt * 64;
#pragma unroll
        for (int i = 0; i < 4; ++i) {
            int o = tid * 16 + i * 4096;
            int row = o >> 7;
            int sg = ((o >> 4) & 7) ^ (row & 7);
            load_lds16(qb + (size_t)(q0 + row) * DF + kc2 + sg * 8, (char*)Abuf + o);
        }
#pragma unroll
        for (int i = 0; i < 4; ++i) {
            int o = tid * 16 + i * 4096;
            int row = o >> 7;
            int sg = ((o >> 4) & 7) ^ (row & 7);
            load_lds16(pbc + (size_t)(n0 + row) * DF + kc2 + sg * 8, (char*)Bbuf + o);
        }
        __syncthreads();
#pragma unroll
        for (int kk2 = 0; kk2 < 2; ++kk2) {
            int u = ((kk2 * 4 + quad) ^ (l15 & 7)) << 4;
            short8 b[8];
#pragma unroll
            for (int nt = 0; nt < 8; ++nt)
                b[nt] = *(const short8*)((const char*)Bbuf + (nt * 16 + l15) * 128 + u);
#pragma unroll
            for (int mt = 0; mt < 2; ++mt) {
                short8 a = *(const short8*)((const char*)Abuf + (w * 32 + mt * 16 + l15) * 128 + u);
#pragma unroll
                for (int nt = 0; nt < 8; ++nt)
                    acc[mt][nt] = __builtin_amdgcn_mfma_f32_16x16x32_bf16(a, b[nt], acc[mt][nt], 0, 0, 0);
            }
        }
        __syncthreads();
    }
#pragma unroll
    for (int mt = 0; mt < 2; ++mt)
#pragma unroll
        for (int reg = 0; reg < 4; ++reg) {
            int row = w * 32 + mt * 16 + quad * 4 + reg;
            float part = 0.f;
#pragma unroll
            for (int nt = 0; nt < 8; ++nt) {
                float h = acc[mt][nt][reg];
                unsigned qu = qb[(size_t)(q0 + row) * DF + n0 + nt * 16 + l15];
                part += h * __uint_as_float(qu << 16);
            }
            part += __shfl_xor(part, 1);
            part += __shfl_xor(part, 2);
            part += __shfl_xor(part, 4);
            part += __shfl_xor(part, 8);
            if (l15 == 0) atomicAdd(&out[(size_t)(q0 + row) * 2 + c], -part);
        }
}

extern "C" void kernel_launch(void* const* d_in, const int* in_sizes, int n_in,
                              void* d_out, int out_size, void* d_ws, size_t ws_size,
                              hipStream_t stream) {
    const float* S = (const float*)d_in[0];
    const int* lab = (const int*)d_in[1];
    const float* Q = (const float*)d_in[2];
    float* out = (float*)d_out;
    float* ws = (float*)d_ws;

    k_front<<<520, 256, 0, stream>>>(S, lab, ws);
    k_asm<<<66, 256, 0, stream>>>(ws);
    k_pm0<<<dim3(28, 2), 256, 0, stream>>>(ws);
    for (int L = 0; L < 4; ++L) {
        if (L) k_prep<<<2, 256, 0, stream>>>(ws, L);
        k_fpair<<<dim3(64, 2), 256, 0, stream>>>(ws, L);
    }
    k_vkbf<<<272, 256, 0, stream>>>(ws);
    k_qinit<<<NQ / 4, 256, 0, stream>>>(Q, ws, out);
    k_gemm<<<dim3(NQ / 128, 8), 256, 0, stream>>>(ws, out);
}

// Round 15
// 343.579 us; speedup vs baseline: 2.0745x; 2.0745x over previous
//
#include <hip/hip_runtime.h>

#define NS 512
#define DF 512
#define NQ 16384

// ws layout (float offsets)
#define WS_MEAN0 0
#define WS_MEAN1 512
#define WS_MEANA 1024
#define WS_CNT   1536
#define WS_V0    2048
#define WS_V1    2560
#define WS_KC    3072
#define WS_M     4096                      // M / P fp32 [2][512][512]
#define WS_PB    (WS_M + 2*DF*DF)          // P bf16 [2][512][512] (as ushort) -- written POST-GJ
#define WS_QB    (WS_PB + DF*DF)           // Q bf16 (written by k_qinit)
#define WS_GP    WS_QB                     // Gp [8][2][512][512] f32 (dead after k_asm; QB overwrites later)
// GJ scratch ALIASES the dead PB region (PB only written after the GJ loop).
// UC[par][c][slot][4096]: U copies; slot k doubles as T-hat_k storage at step k.
// VC[par][c][slot][4096]: V copies. Total = 262144 floats = exactly PB's size.
#define WS_UC    WS_PB
#define WS_VC    (WS_PB + 2*2*8*4096)

typedef __attribute__((ext_vector_type(8))) short short8;
typedef __attribute__((ext_vector_type(4))) float floatx4;

__device__ __forceinline__ unsigned short f2bf(float f) {
    unsigned u = __float_as_uint(f);
    unsigned r = (u + 0x7fffu + ((u >> 16) & 1u)) >> 16;
    return (unsigned short)r;
}

// readlane for float: raw builtin takes i32 -> bitcast explicitly (R5 bug).
__device__ __forceinline__ float readlane_f(float v, int lane) {
    return __uint_as_float(__builtin_amdgcn_readlane(__float_as_uint(v), lane));
}

__device__ __forceinline__ void load_lds16(const void* g, void* l) {
    __builtin_amdgcn_global_load_lds(
        (const __attribute__((address_space(1))) unsigned int*)g,
        (__attribute__((address_space(3))) unsigned int*)l, 16, 0, 0);
}

// -------- shared: 64x64 SPD Gauss-Jordan inversion of LDS T (stride 66) --------
// 16 rounds of 4 pivots; 256 threads (4 waves, each owns 16 rows).
__device__ __forceinline__ void gj_invert64(float* T, float (*rbuf)[4][64], int tid) {
    int jl = tid & 63, w = tid >> 6;
    float Tr[16];
#pragma unroll
    for (int m = 0; m < 16; ++m) Tr[m] = T[(w * 16 + m) * 66 + jl];
#pragma unroll
    for (int r = 0; r < 16; ++r) {
        const int q0 = r * 4;
        const int par = r & 1;
        if (w == (q0 >> 4)) {
            const int mb = q0 & 15;
            rbuf[par][0][jl] = Tr[mb + 0];
            rbuf[par][1][jl] = Tr[mb + 1];
            rbuf[par][2][jl] = Tr[mb + 2];
            rbuf[par][3][jl] = Tr[mb + 3];
        }
        __syncthreads();
        float B[4][4];
#pragma unroll
        for (int a = 0; a < 4; ++a)
#pragma unroll
            for (int bb = 0; bb < 4; ++bb) B[a][bb] = rbuf[par][a][q0 + bb];
#pragma unroll
        for (int p = 0; p < 4; ++p) {
            float piv = 1.0f / B[p][p];
#pragma unroll
            for (int j = 0; j < 4; ++j) if (j != p) B[p][j] *= piv;
#pragma unroll
            for (int i = 0; i < 4; ++i) if (i != p) {
                float f = B[i][p];
#pragma unroll
                for (int j = 0; j < 4; ++j) if (j != p) B[i][j] -= f * B[p][j];
                B[i][p] = -f * piv;
            }
            B[p][p] = piv;
        }
        float r0v = rbuf[par][0][jl], r1v = rbuf[par][1][jl];
        float r2v = rbuf[par][2][jl], r3v = rbuf[par][3][jl];
        float nr[4];
#pragma unroll
        for (int a = 0; a < 4; ++a)
            nr[a] = B[a][0] * r0v + B[a][1] * r1v + B[a][2] * r2v + B[a][3] * r3v;
        bool colin = ((jl >> 2) == r);
        int bsel = jl & 3;
        float Bc[4];
#pragma unroll
        for (int a = 0; a < 4; ++a)
            Bc[a] = bsel == 0 ? B[a][0]
                  : (bsel == 1 ? B[a][1] : (bsel == 2 ? B[a][2] : B[a][3]));
#pragma unroll
        for (int m = 0; m < 16; ++m) {
            float cv0 = readlane_f(Tr[m], q0 + 0);
            float cv1 = readlane_f(Tr[m], q0 + 1);
            float cv2 = readlane_f(Tr[m], q0 + 2);
            float cv3 = readlane_f(Tr[m], q0 + 3);
            float g = Tr[m] - (cv0 * nr[0] + cv1 * nr[1] + cv2 * nr[2] + cv3 * nr[3]);
            bool rowin = (((w * 16 + m) >> 2) == r);
            float gcol = -(cv0 * Bc[0] + cv1 * Bc[1] + cv2 * Bc[2] + cv3 * Bc[3]);
            if (rowin) g = nr[m & 3];
            if (colin) g = rowin ? Bc[m & 3] : gcol;
            Tr[m] = g;
        }
    }
#pragma unroll
    for (int m = 0; m < 16; ++m) T[(w * 16 + m) * 66 + jl] = Tr[m];
    __syncthreads();
}

// ---------------- K1: fused stats (blocks 512..519) + masked Grams (0..511) ----------------
__global__ __launch_bounds__(256) void k_front(const float* __restrict__ S,
                                               const int* __restrict__ lab,
                                               float* __restrict__ ws) {
    int b = blockIdx.x, tid = threadIdx.x;
    if (b >= 512) {
        __shared__ int slb[NS];
        __shared__ float r0[4][64], r1[4][64];
        __shared__ int rc[4];
        int bs = b - 512;
        for (int l = tid; l < NS; l += 256) slb[l] = lab[l];
        __syncthreads();
        int dl = tid & 63, ch = tid >> 6;
        int dd = bs * 64 + dl;
        float s0 = 0.f, s1 = 0.f;
        int n1 = 0;
        for (int n = ch * 128; n < ch * 128 + 128; ++n) {
            float v = S[n * DF + dd];
            if (slb[n]) { s1 += v; n1++; } else { s0 += v; }
        }
        r0[ch][dl] = s0; r1[ch][dl] = s1;
        if (dl == 0) rc[ch] = n1;
        __syncthreads();
        if (ch == 0) {
            float t0 = 0.f, t1 = 0.f; int n1t = 0;
#pragma unroll
            for (int x = 0; x < 4; ++x) { t0 += r0[x][dl]; t1 += r1[x][dl]; n1t += rc[x]; }
            float fn1 = (float)n1t, fn0 = (float)(NS - n1t);
            ws[WS_MEAN0 + dd] = t0 / fn0;
            ws[WS_MEAN1 + dd] = t1 / fn1;
            ws[WS_MEANA + dd] = (t0 + t1) / (float)NS;
            if (bs == 0 && dl == 0) {
                ws[WS_CNT] = fn0; ws[WS_CNT + 1] = fn1;
                ws[WS_KC] = 0.f; ws[WS_KC + 1] = 0.f;
            }
        }
        return;
    }
    __shared__ float SA[16 * 65];
    __shared__ float SB[16 * 65];
    __shared__ int lb[16];
    int tx = tid & 15, ty = tid >> 4;
    int i0 = (b & 7) * 64, j0 = ((b >> 3) & 7) * 64;
    int z = b >> 6;
    float a0[4][4] = {{0.f}}, a1[4][4] = {{0.f}};
    for (int nc = z * 64; nc < z * 64 + 64; nc += 16) {
#pragma unroll
        for (int l = 0; l < 4; ++l) {
            int idx = tid + 256 * l;
            int nn = idx >> 6, col = idx & 63;
            SA[nn * 65 + col] = S[(nc + nn) * DF + i0 + col];
            SB[nn * 65 + col] = S[(nc + nn) * DF + j0 + col];
        }
        if (tid < 16) lb[tid] = lab[nc + tid];
        __syncthreads();
#pragma unroll
        for (int kk = 0; kk < 16; ++kk) {
            float av[4], bv[4];
#pragma unroll
            for (int r = 0; r < 4; ++r) av[r] = SA[kk * 65 + ty * 4 + r];
#pragma unroll
            for (int s = 0; s < 4; ++s) bv[s] = SB[kk * 65 + tx * 4 + s];
            if (lb[kk]) {
#pragma unroll
                for (int r = 0; r < 4; ++r)
#pragma unroll
                    for (int s = 0; s < 4; ++s) a1[r][s] += av[r] * bv[s];
            } else {
#pragma unroll
                for (int r = 0; r < 4; ++r)
#pragma unroll
                    for (int s = 0; s < 4; ++s) a0[r][s] += av[r] * bv[s];
            }
        }
        __syncthreads();
    }
    float* Gp = ws + WS_GP;
#pragma unroll
    for (int r = 0; r < 4; ++r) {
        int i = i0 + ty * 4 + r;
#pragma unroll
        for (int s = 0; s < 4; ++s) {
            int j = j0 + tx * 4 + s;
            Gp[((z * 2 + 0) * DF + i) * DF + j] = a0[r][s];
            Gp[((z * 2 + 1) * DF + i) * DF + j] = a1[r][s];
        }
    }
}

// ---------------- K2: assemble M_c (64x64 tile blocks) + k=0 copies + pivot-0 inversions ----------------
// b<64: tile (ti=b>>3, tj=b&7), both classes; writes M and, for row-0/col-0
// tiles, the step-0 U/V copies (parity 0, aliasing dead PB). b==0 inverts its
// class-0 tile -> UC[0][0][slot 0]; b==64 recomputes tile(0,0) class 1 and
// inverts -> UC[0][1][slot 0]. All dependencies intra-block -> race-free.
__global__ __launch_bounds__(256) void k_asm(float* __restrict__ ws) {
    int b = blockIdx.x, tid = threadIdx.x;
    int tx = tid & 15, ty = tid >> 4;
    __shared__ float T[64 * 66];
    __shared__ float rbuf[2][4][64];
    const float* Gp = ws + WS_GP;
    float n0 = ws[WS_CNT], n1 = ws[WS_CNT + 1];
    float lam0 = fminf(n0 / (n0 + 1.f), 0.1f);
    float lam1 = fminf(n1 / (n1 + 1.f), 0.1f);
    bool dup = (b == 64);
    int ti = dup ? 0 : (b >> 3), tj = dup ? 0 : (b & 7);
    int jb = tj * 64 + tx * 4;
    float4 m0j = *(const float4*)&ws[WS_MEAN0 + jb];
    float4 m1j = *(const float4*)&ws[WS_MEAN1 + jb];
    float4 maj = *(const float4*)&ws[WS_MEANA + jb];
    float out0[4][4], out1[4][4];
#pragma unroll
    for (int r = 0; r < 4; ++r) {
        int i = ti * 64 + ty * 4 + r;
        float m0i = ws[WS_MEAN0 + i], m1i = ws[WS_MEAN1 + i], mai = ws[WS_MEANA + i];
        float4 g0 = make_float4(0.f, 0.f, 0.f, 0.f);
        float4 g1 = make_float4(0.f, 0.f, 0.f, 0.f);
#pragma unroll
        for (int ch = 0; ch < 8; ++ch) {
            float4 a = *(const float4*)&Gp[((ch * 2 + 0) * DF + i) * DF + jb];
            float4 bb = *(const float4*)&Gp[((ch * 2 + 1) * DF + i) * DF + jb];
            g0.x += a.x; g0.y += a.y; g0.z += a.z; g0.w += a.w;
            g1.x += bb.x; g1.y += bb.y; g1.z += bb.z; g1.w += bb.w;
        }
        float g0a[4] = {g0.x, g0.y, g0.z, g0.w};
        float g1a[4] = {g1.x, g1.y, g1.z, g1.w};
        float m0ja[4] = {m0j.x, m0j.y, m0j.z, m0j.w};
        float m1ja[4] = {m1j.x, m1j.y, m1j.z, m1j.w};
        float maja[4] = {maj.x, maj.y, maj.z, maj.w};
#pragma unroll
        for (int s = 0; s < 4; ++s) {
            int j = jb + s;
            float task = (g0a[s] + g1a[s] - (float)NS * mai * maja[s]) / (float)(NS - 1);
            float cov0 = (g0a[s] - n0 * m0i * m0ja[s]) / (n0 - 1.f);
            float cov1 = (g1a[s] - n1 * m1i * m1ja[s]) / (n1 - 1.f);
            float dg = (i == j) ? 0.1f : 0.f;
            out0[r][s] = lam0 * cov0 + (1.f - lam0) * task + dg;
            out1[r][s] = lam1 * cov1 + (1.f - lam1) * task + dg;
        }
    }
    if (!dup) {
#pragma unroll
        for (int r = 0; r < 4; ++r) {
            int i = ti * 64 + ty * 4 + r;
            *(float4*)&ws[WS_M + (size_t)i * DF + jb] = make_float4(out0[r][0], out0[r][1], out0[r][2], out0[r][3]);
            *(float4*)&ws[WS_M + DF * DF + (size_t)i * DF + jb] = make_float4(out1[r][0], out1[r][1], out1[r][2], out1[r][3]);
        }
        // step-0 copies (parity 0): U = M[0][tj], V = M[ti][0]
        if (ti == 0 && tj != 0) {
            float* u0 = ws + WS_UC + ((0 * 2 + 0) * 8 + tj) * 4096;
            float* u1 = ws + WS_UC + ((0 * 2 + 1) * 8 + tj) * 4096;
#pragma unroll
            for (int r = 0; r < 4; ++r) {
                int il = ty * 4 + r, jl = tx * 4;
                *(float4*)&u0[il * 64 + jl] = make_float4(out0[r][0], out0[r][1], out0[r][2], out0[r][3]);
                *(float4*)&u1[il * 64 + jl] = make_float4(out1[r][0], out1[r][1], out1[r][2], out1[r][3]);
            }
        }
        if (tj == 0 && ti != 0) {
            float* v0 = ws + WS_VC + ((0 * 2 + 0) * 8 + ti) * 4096;
            float* v1 = ws + WS_VC + ((0 * 2 + 1) * 8 + ti) * 4096;
#pragma unroll
            for (int r = 0; r < 4; ++r) {
                int il = ty * 4 + r, jl = tx * 4;
                *(float4*)&v0[il * 64 + jl] = make_float4(out0[r][0], out0[r][1], out0[r][2], out0[r][3]);
                *(float4*)&v1[il * 64 + jl] = make_float4(out1[r][0], out1[r][1], out1[r][2], out1[r][3]);
            }
        }
    }
    if (b == 0 || dup) {
        // invert own tile(0,0): class 0 for b==0, class 1 for b==64
#pragma unroll
        for (int r = 0; r < 4; ++r)
#pragma unroll
            for (int s = 0; s < 4; ++s)
                T[(ty * 4 + r) * 66 + tx * 4 + s] = dup ? out1[r][s] : out0[r][s];
        __syncthreads();
        gj_invert64(T, rbuf, tid);
        float* scr = ws + WS_UC + ((0 * 2 + (dup ? 1 : 0)) * 8 + 0) * 4096;   // T-hat_0 in slot 0
#pragma unroll
        for (int m = 0; m < 16; ++m) {
            int idx = tid + 256 * m;
            int i = idx >> 6, j = idx & 63;
            scr[i * 64 + j] = T[i * 66 + j];
        }
    }
}

// ---------------- K3: fused GJ step (ONE launch per k) ----------------
// Trailing blocks read U/V from parity copies (written last launch), so
// row/col blocks may overwrite M in the same launch. T-hat_k lives in UC
// slot k (never read as a U operand at step k). Blocks writing tiles in
// row/col k+1 also write next-parity copies; the special block (k+1,k+1)
// computes its trailing value, inverts it, and stores T-hat_{k+1} in UCo
// slot k+1 (written by no other block this step).
__global__ __launch_bounds__(256) void k_fgj(float* __restrict__ ws, int k) {
    int c = blockIdx.y, jh = blockIdx.z;
    int x = blockIdx.x;
    int ti = x >> 3, tj = x & 7;
    int par = k & 1, npar = par ^ 1;
    int tid = threadIdx.x;
    int cb0 = jh * 32;
    float* Mb = ws + WS_M + (size_t)c * DF * DF;
    const float* UCi = ws + WS_UC + (par * 2 + c) * 8 * 4096;
    const float* VCi = ws + WS_VC + (par * 2 + c) * 8 * 4096;
    float* UCo = ws + WS_UC + (npar * 2 + c) * 8 * 4096;
    float* VCo = ws + WS_VC + (npar * 2 + c) * 8 * 4096;
    const float* scr_in = UCi + k * 4096;       // T-hat_k

    if (ti == k && tj == k) {
        float* Akk = Mb + (k * 64) * DF + k * 64;
#pragma unroll
        for (int m = 0; m < 8; ++m) {
            int idx = tid + 256 * m;     // 64 x 32
            int i = idx >> 5, j = idx & 31;
            Akk[i * DF + cb0 + j] = scr_in[i * 64 + cb0 + j];
        }
        return;
    }
    bool isrow = (ti == k);
    bool iscol = (tj == k);
    bool spec = (ti == k + 1) && (tj == k + 1);
    if ((iscol || spec) && jh == 1) return;

    __shared__ float T[64 * 68];
    __shared__ float V[64 * 66];
    __shared__ float U[64 * 68];
    __shared__ float D[64 * 68];
    __shared__ float rbuf[2][4][64];

    // stage T-hat (stride 68 -> float4 column reads aligned)
#pragma unroll
    for (int m = 0; m < 16; ++m) {
        int idx = tid + 256 * m;
        int i = idx >> 6, j = idx & 63;
        T[i * 68 + j] = scr_in[i * 64 + j];
    }

    if (isrow) {
        // row: M[k][tj] = T-hat * U_old (half jh)
        const float* uc = UCi + tj * 4096;
#pragma unroll
        for (int m = 0; m < 8; ++m) {
            int idx = tid + 256 * m;
            int i = idx >> 5, j = idx & 31;
            U[i * 68 + j] = uc[i * 64 + cb0 + j];
        }
        __syncthreads();
        int tx8 = tid & 7, ty32 = tid >> 3;
        float acc[2][4] = {{0.f}};
#pragma unroll 8
        for (int kk = 0; kk < 64; ++kk) {
            float a0 = T[(ty32 * 2 + 0) * 68 + kk];
            float a1 = T[(ty32 * 2 + 1) * 68 + kk];
            float4 bv = *(const float4*)&U[kk * 68 + tx8 * 4];
            acc[0][0] += a0 * bv.x; acc[0][1] += a0 * bv.y; acc[0][2] += a0 * bv.z; acc[0][3] += a0 * bv.w;
            acc[1][0] += a1 * bv.x; acc[1][1] += a1 * bv.y; acc[1][2] += a1 * bv.z; acc[1][3] += a1 * bv.w;
        }
        float* dst = Mb + (k * 64) * DF + tj * 64 + cb0;
#pragma unroll
        for (int r = 0; r < 2; ++r) {
            int row = ty32 * 2 + r;
            float4 o = make_float4(acc[r][0], acc[r][1], acc[r][2], acc[r][3]);
            *(float4*)&dst[row * DF + tx8 * 4] = o;
            if (tj == k + 1)
                *(float4*)&VCo[k * 4096 + row * 64 + cb0 + tx8 * 4] = o;
        }
        return;
    }

    if (iscol) {
        // col: M[ti][k] = -V_old * T-hat (full tile, one block)
        const float* vc = VCi + ti * 4096;
#pragma unroll
        for (int m = 0; m < 16; ++m) {
            int idx = tid + 256 * m;
            int i = idx >> 6, j = idx & 63;
            V[i * 66 + j] = vc[i * 64 + j];
        }
        __syncthreads();
        int tx16 = tid & 15, ty16 = tid >> 4;
        float acc[4][4] = {{0.f}};
#pragma unroll 8
        for (int kk = 0; kk < 64; ++kk) {
            float a[4];
#pragma unroll
            for (int r = 0; r < 4; ++r) a[r] = V[(ty16 * 4 + r) * 66 + kk];
            float4 bv = *(const float4*)&T[kk * 68 + tx16 * 4];
#pragma unroll
            for (int r = 0; r < 4; ++r) {
                acc[r][0] += a[r] * bv.x; acc[r][1] += a[r] * bv.y;
                acc[r][2] += a[r] * bv.z; acc[r][3] += a[r] * bv.w;
            }
        }
        float* dst = Mb + (ti * 64) * DF + k * 64;
#pragma unroll
        for (int r = 0; r < 4; ++r) {
            int row = ty16 * 4 + r;
            float4 o = make_float4(-acc[r][0], -acc[r][1], -acc[r][2], -acc[r][3]);
            *(float4*)&dst[row * DF + tx16 * 4] = o;
            if (ti == k + 1)
                *(float4*)&UCo[k * 4096 + row * 64 + tx16 * 4] = o;
        }
        return;
    }

    if (!spec) {
        // trailing half-tile: D = T-hat*U_half; Y -= V*D
        const float* vc = VCi + ti * 4096;
#pragma unroll
        for (int m = 0; m < 16; ++m) {
            int idx = tid + 256 * m;
            int i = idx >> 6, j = idx & 63;
            V[i * 66 + j] = vc[i * 64 + j];
        }
        const float* uc = UCi + tj * 4096;
#pragma unroll
        for (int m = 0; m < 8; ++m) {
            int idx = tid + 256 * m;
            int i = idx >> 5, j = idx & 31;
            U[i * 68 + j] = uc[i * 64 + cb0 + j];
        }
        __syncthreads();
        int tx8 = tid & 7, ty32 = tid >> 3;
        float a1[2][4] = {{0.f}};
#pragma unroll 8
        for (int kk = 0; kk < 64; ++kk) {
            float v0 = T[(ty32 * 2 + 0) * 68 + kk];
            float v1 = T[(ty32 * 2 + 1) * 68 + kk];
            float4 bv = *(const float4*)&U[kk * 68 + tx8 * 4];
            a1[0][0] += v0 * bv.x; a1[0][1] += v0 * bv.y; a1[0][2] += v0 * bv.z; a1[0][3] += v0 * bv.w;
            a1[1][0] += v1 * bv.x; a1[1][1] += v1 * bv.y; a1[1][2] += v1 * bv.z; a1[1][3] += v1 * bv.w;
        }
#pragma unroll
        for (int r = 0; r < 2; ++r)
            *(float4*)&D[(ty32 * 2 + r) * 68 + tx8 * 4] = make_float4(a1[r][0], a1[r][1], a1[r][2], a1[r][3]);
        __syncthreads();
        float a2[2][4] = {{0.f}};
#pragma unroll 8
        for (int kk = 0; kk < 64; ++kk) {
            float v0 = V[(ty32 * 2 + 0) * 66 + kk];
            float v1 = V[(ty32 * 2 + 1) * 66 + kk];
            float4 bv = *(const float4*)&D[kk * 68 + tx8 * 4];
            a2[0][0] += v0 * bv.x; a2[0][1] += v0 * bv.y; a2[0][2] += v0 * bv.z; a2[0][3] += v0 * bv.w;
            a2[1][0] += v1 * bv.x; a2[1][1] += v1 * bv.y; a2[1][2] += v1 * bv.z; a2[1][3] += v1 * bv.w;
        }
        float* dst = Mb + (ti * 64) * DF + tj * 64 + cb0;
#pragma unroll
        for (int r = 0; r < 2; ++r) {
            int row = ty32 * 2 + r;
            float4 old = *(const float4*)&dst[row * DF + tx8 * 4];
            float4 nv = make_float4(old.x - a2[r][0], old.y - a2[r][1], old.z - a2[r][2], old.w - a2[r][3]);
            *(float4*)&dst[row * DF + tx8 * 4] = nv;
            if (tj == k + 1)
                *(float4*)&VCo[ti * 4096 + row * 64 + cb0 + tx8 * 4] = nv;
            if (ti == k + 1)
                *(float4*)&UCo[tj * 4096 + row * 64 + cb0 + tx8 * 4] = nv;
        }
        return;
    }

    // special (k+1,k+1), exists only for k<7: full trailing value, then
    // invert -> UCo slot k+1 (= T-hat_{k+1}).
    {
        const float* vc = VCi + (k + 1) * 4096;
#pragma unroll
        for (int m = 0; m < 16; ++m) {
            int idx = tid + 256 * m;
            int i = idx >> 6, j = idx & 63;
            V[i * 66 + j] = vc[i * 64 + j];
        }
        const float* uc = UCi + (k + 1) * 4096;
#pragma unroll
        for (int m = 0; m < 16; ++m) {
            int idx = tid + 256 * m;
            int i = idx >> 6, j = idx & 63;
            U[i * 68 + j] = uc[i * 64 + j];
        }
        __syncthreads();
        int tx16 = tid & 15, ty16 = tid >> 4;
        float d[4][4] = {{0.f}};
#pragma unroll 8
        for (int kk = 0; kk < 64; ++kk) {
            float a[4];
#pragma unroll
            for (int r = 0; r < 4; ++r) a[r] = T[(ty16 * 4 + r) * 68 + kk];
            float4 bv = *(const float4*)&U[kk * 68 + tx16 * 4];
#pragma unroll
            for (int r = 0; r < 4; ++r) {
                d[r][0] += a[r] * bv.x; d[r][1] += a[r] * bv.y;
                d[r][2] += a[r] * bv.z; d[r][3] += a[r] * bv.w;
            }
        }
#pragma unroll
        for (int r = 0; r < 4; ++r)
            *(float4*)&D[(ty16 * 4 + r) * 68 + tx16 * 4] = make_float4(d[r][0], d[r][1], d[r][2], d[r][3]);
        __syncthreads();
        float y[4][4] = {{0.f}};
#pragma unroll 8
        for (int kk = 0; kk < 64; ++kk) {
            float a[4];
#pragma unroll
            for (int r = 0; r < 4; ++r) a[r] = V[(ty16 * 4 + r) * 66 + kk];
            float4 bv = *(const float4*)&D[kk * 68 + tx16 * 4];
#pragma unroll
            for (int r = 0; r < 4; ++r) {
                y[r][0] += a[r] * bv.x; y[r][1] += a[r] * bv.y;
                y[r][2] += a[r] * bv.z; y[r][3] += a[r] * bv.w;
            }
        }
        const float* dst = Mb + (size_t)((k + 1) * 64) * DF + (k + 1) * 64;
        float4 nv[4];
#pragma unroll
        for (int r = 0; r < 4; ++r) {
            int row = ty16 * 4 + r;
            float4 old = *(const float4*)&dst[row * DF + tx16 * 4];
            nv[r] = make_float4(old.x - y[r][0], old.y - y[r][1], old.z - y[r][2], old.w - y[r][3]);
        }
        __syncthreads();   // all V reads done before overwrite
#pragma unroll
        for (int r = 0; r < 4; ++r) {
            int row = ty16 * 4 + r;
            V[row * 66 + tx16 * 4 + 0] = nv[r].x;
            V[row * 66 + tx16 * 4 + 1] = nv[r].y;
            V[row * 66 + tx16 * 4 + 2] = nv[r].z;
            V[row * 66 + tx16 * 4 + 3] = nv[r].w;
        }
        __syncthreads();
        gj_invert64(V, rbuf, tid);
        float* so = UCo + (k + 1) * 4096;
#pragma unroll
        for (int m = 0; m < 16; ++m) {
            int idx = tid + 256 * m;
            int i = idx >> 6, j = idx & 63;
            so[i * 64 + j] = V[i * 66 + j];
        }
    }
}

// ---------------- K4: v_c/k_c (blocks 0..15) + P fp32 -> bf16 (blocks 16..271) ----------------
__global__ __launch_bounds__(256) void k_vkbf(float* __restrict__ ws) {
    int b = blockIdx.x;
    int tid = threadIdx.x;
    if (b >= 16) {
        // convert M [2][512][512] fp32 -> PB bf16 (overwrites the dead GJ scratch)
        int e = (b - 16) * 2048 + tid * 8;
        const float* M = ws + WS_M;
        unsigned short* pbw = (unsigned short*)(ws + WS_PB);
        float4 x0 = *(const float4*)&M[e];
        float4 x1 = *(const float4*)&M[e + 4];
        short8 r;
        r[0] = (short)f2bf(x0.x); r[1] = (short)f2bf(x0.y);
        r[2] = (short)f2bf(x0.z); r[3] = (short)f2bf(x0.w);
        r[4] = (short)f2bf(x1.x); r[5] = (short)f2bf(x1.y);
        r[6] = (short)f2bf(x1.z); r[7] = (short)f2bf(x1.w);
        *(short8*)(pbw + e) = r;
        return;
    }
    int c = b >> 3, rb = b & 7;
    const float* P = ws + WS_M + (size_t)c * DF * DF;
    const float* mc = ws + (c ? WS_MEAN1 : WS_MEAN0);
    float* v = ws + (c ? WS_V1 : WS_V0);
    __shared__ float ml[DF];
    __shared__ float red[4][64];
    for (int l = tid; l < DF; l += 256) ml[l] = mc[l];
    __syncthreads();
    int rl = tid & 63, ch = tid >> 6;
    int row = rb * 64 + rl;
    float dot = 0.f;
    const float* pr = P + (size_t)row * DF + ch * 128;
    for (int t = 0; t < 32; ++t) {
        float4 pv = *(const float4*)(pr + t * 4);
        const float* mm = ml + ch * 128 + t * 4;
        dot += pv.x * mm[0] + pv.y * mm[1] + pv.z * mm[2] + pv.w * mm[3];
    }
    red[ch][rl] = dot;
    __syncthreads();
    if (ch == 0) {
        float d = red[0][rl] + red[1][rl] + red[2][rl] + red[3][rl];
        v[row] = d;
        float kp = d * ml[row];
#pragma unroll
        for (int off = 32; off > 0; off >>= 1) kp += __shfl_down(kp, off);
        if (rl == 0) atomicAdd(&ws[WS_KC + c], kp);
    }
}

// ---------------- K5: fused Q->bf16 + logits init ----------------
__global__ __launch_bounds__(256) void k_qinit(const float* __restrict__ Q,
                                               float* __restrict__ ws,
                                               float* __restrict__ out) {
    unsigned short* qbw = (unsigned short*)(ws + WS_QB);
    const float* v0 = ws + WS_V0;
    const float* v1 = ws + WS_V1;
    int lane = threadIdx.x & 63;
    int q = blockIdx.x * 4 + (threadIdx.x >> 6);
    const float* qrow = Q + (size_t)q * DF + lane * 8;
    float4 x0 = *(const float4*)(qrow);
    float4 x1 = *(const float4*)(qrow + 4);
    const float* v0p = v0 + lane * 8;
    const float* v1p = v1 + lane * 8;
    float4 w00 = *(const float4*)(v0p), w01 = *(const float4*)(v0p + 4);
    float4 w10 = *(const float4*)(v1p), w11 = *(const float4*)(v1p + 4);
    float a0 = x0.x * w00.x + x0.y * w00.y + x0.z * w00.z + x0.w * w00.w
             + x1.x * w01.x + x1.y * w01.y + x1.z * w01.z + x1.w * w01.w;
    float a1 = x0.x * w10.x + x0.y * w10.y + x0.z * w10.z + x0.w * w10.w
             + x1.x * w11.x + x1.y * w11.y + x1.z * w11.z + x1.w * w11.w;
    short8 r;
    r[0] = (short)f2bf(x0.x); r[1] = (short)f2bf(x0.y);
    r[2] = (short)f2bf(x0.z); r[3] = (short)f2bf(x0.w);
    r[4] = (short)f2bf(x1.x); r[5] = (short)f2bf(x1.y);
    r[6] = (short)f2bf(x1.z); r[7] = (short)f2bf(x1.w);
    *(short8*)(qbw + (size_t)q * DF + lane * 8) = r;
#pragma unroll
    for (int off = 32; off > 0; off >>= 1) {
        a0 += __shfl_down(a0, off);
        a1 += __shfl_down(a1, off);
    }
    if (lane == 0) {
        out[q * 2 + 0] = 2.f * a0 - ws[WS_KC + 0];
        out[q * 2 + 1] = 2.f * a1 - ws[WS_KC + 1];
    }
}

// ---------------- K6: MFMA GEMM, 128x128 tile, LDS staging + swizzle ----------------
__global__ __launch_bounds__(256, 3) void k_gemm(const float* __restrict__ ws,
                                                 float* __restrict__ out) {
    const unsigned short* qb = (const unsigned short*)(ws + WS_QB);
    int c = blockIdx.y >> 2;
    int n0 = (blockIdx.y & 3) * 128;
    const unsigned short* pbc = (const unsigned short*)(ws + WS_PB) + (size_t)c * DF * DF;
    int q0 = blockIdx.x * 128;
    __shared__ __align__(16) unsigned short Abuf[128 * 64];   // 16 KB
    __shared__ __align__(16) unsigned short Bbuf[128 * 64];   // 16 KB
    int tid = threadIdx.x;
    int w = tid >> 6, lane = tid & 63;
    int quad = lane >> 4, l15 = lane & 15;
    floatx4 acc[2][8];
#pragma unroll
    for (int mt = 0; mt < 2; ++mt)
#pragma unroll
        for (int nt = 0; nt < 8; ++nt) acc[mt][nt] = (floatx4)(0.f);

    for (int kt = 0; kt < 8; ++kt) {
        int kc2 = kt * 64;
#pragma unroll
        for (int i = 0; i < 4; ++i) {
            int o = tid * 16 + i * 4096;
            int row = o >> 7;
            int sg = ((o >> 4) & 7) ^ (row & 7);
            load_lds16(qb + (size_t)(q0 + row) * DF + kc2 + sg * 8, (char*)Abuf + o);
        }
#pragma unroll
        for (int i = 0; i < 4; ++i) {
            int o = tid * 16 + i * 4096;
            int row = o >> 7;
            int sg = ((o >> 4) & 7) ^ (row & 7);
            load_lds16(pbc + (size_t)(n0 + row) * DF + kc2 + sg * 8, (char*)Bbuf + o);
        }
        __syncthreads();
#pragma unroll
        for (int kk2 = 0; kk2 < 2; ++kk2) {
            int u = ((kk2 * 4 + quad) ^ (l15 & 7)) << 4;   // swizzled 16B seg offset
            short8 b[8];
#pragma unroll
            for (int nt = 0; nt < 8; ++nt)
                b[nt] = *(const short8*)((const char*)Bbuf + (nt * 16 + l15) * 128 + u);
#pragma unroll
            for (int mt = 0; mt < 2; ++mt) {
                short8 a = *(const short8*)((const char*)Abuf + (w * 32 + mt * 16 + l15) * 128 + u);
#pragma unroll
                for (int nt = 0; nt < 8; ++nt)
                    acc[mt][nt] = __builtin_amdgcn_mfma_f32_16x16x32_bf16(a, b[nt], acc[mt][nt], 0, 0, 0);
            }
        }
        __syncthreads();
    }
#pragma unroll
    for (int mt = 0; mt < 2; ++mt)
#pragma unroll
        for (int reg = 0; reg < 4; ++reg) {
            int row = w * 32 + mt * 16 + quad * 4 + reg;
            float part = 0.f;
#pragma unroll
            for (int nt = 0; nt < 8; ++nt) {
                float h = acc[mt][nt][reg];
                unsigned qu = qb[(size_t)(q0 + row) * DF + n0 + nt * 16 + l15];
                part += h * __uint_as_float(qu << 16);
            }
            part += __shfl_xor(part, 1);
            part += __shfl_xor(part, 2);
            part += __shfl_xor(part, 4);
            part += __shfl_xor(part, 8);
            if (l15 == 0) atomicAdd(&out[(size_t)(q0 + row) * 2 + c], -part);
        }
}

extern "C" void kernel_launch(void* const* d_in, const int* in_sizes, int n_in,
                              void* d_out, int out_size, void* d_ws, size_t ws_size,
                              hipStream_t stream) {
    const float* S = (const float*)d_in[0];
    const int* lab = (const int*)d_in[1];
    const float* Q = (const float*)d_in[2];
    float* out = (float*)d_out;
    float* ws = (float*)d_ws;

    k_front<<<520, 256, 0, stream>>>(S, lab, ws);
    k_asm<<<65, 256, 0, stream>>>(ws);
    for (int k = 0; k < 8; ++k)
        k_fgj<<<dim3(64, 2, 2), 256, 0, stream>>>(ws, k);
    k_vkbf<<<272, 256, 0, stream>>>(ws);
    k_qinit<<<NQ / 4, 256, 0, stream>>>(Q, ws, out);
    k_gemm<<<dim3(NQ / 128, 8), 256, 0, stream>>>(ws, out);
}